// Round 14
// baseline (530.218 us; speedup 1.0000x reference)
//
#include <hip/hip_runtime.h>
#include <stdint.h>

#define NB 64
#define NO 32
#define NI 512
#define ND 64

typedef __attribute__((ext_vector_type(8))) short short8;
typedef __attribute__((ext_vector_type(4))) float f32x4;

// async global->LDS DMA, 16 B/lane. Global addr per-lane; LDS base wave-uniform,
// lane i lands at base + 16*i (m104/m108 semantics).
#define GL2LDS(g, s) __builtin_amdgcn_global_load_lds( \
    (const __attribute__((address_space(1))) void*)(g), \
    (__attribute__((address_space(3))) void*)(s), 16, 0, 0)

__device__ __forceinline__ float blo(unsigned int u) {
    union { unsigned int i; float f; } v; v.i = u << 16; return v.f;
}
__device__ __forceinline__ float bhi(unsigned int u) {
    union { unsigned int i; float f; } v; v.i = u & 0xFFFF0000u; return v.f;
}
__device__ __forceinline__ unsigned short f2bf(float f) {
    union { float f; unsigned int i; } v; v.f = f;
    return (unsigned short)((v.i + 0x7FFFu + ((v.i >> 16) & 1u)) >> 16);
}
__device__ __forceinline__ short8 pack8(const float4 a, const float4 b) {
    short8 r;
    r[0] = (short)f2bf(a.x); r[1] = (short)f2bf(a.y);
    r[2] = (short)f2bf(a.z); r[3] = (short)f2bf(a.w);
    r[4] = (short)f2bf(b.x); r[5] = (short)f2bf(b.y);
    r[6] = (short)f2bf(b.z); r[7] = (short)f2bf(b.w);
    return r;
}
__device__ __forceinline__ void ld_a(float4 r[4], const float* __restrict__ p) {
    r[0] = *(const float4*)(p);
    r[1] = *(const float4*)(p + 4);
    r[2] = *(const float4*)(p + 32);
    r[3] = *(const float4*)(p + 36);
}

// K1: x_hat = W x, stored bf16 in PERMUTED d-order: d' = 4c + td (d = 16 td + c).
// Layout xh[o][b][i][d']. Counted-vmcnt double-buffer pipeline (r10/r11
// verified: 200 -> <157 us; dbuf neutral vs tbuf, kept for smaller LDS).
__global__ __launch_bounds__(256) void k_gemm(const float* __restrict__ x,
                                              const float* __restrict__ w,
                                              unsigned short* __restrict__ xh) {
    __shared__ float Wl[2][4096];            // 32 KB, double-buffered W tiles
    const int o  = blockIdx.x & 31;
    const int ig = blockIdx.x >> 5;
    const int t  = threadIdx.x;
    const int wv = t >> 6;
    const int l  = t & 63;
    const int q  = l >> 4;
    const int c  = l & 15;

    const float* wbase = w + ((size_t)o * NI + ig * 8) * 4096;

    auto stage = [&](int buf, int ii) {
        const float* src = wbase + (size_t)ii * 4096;
        #pragma unroll
        for (int k = 0; k < 4; ++k) {
            const int s = wv * 256 + k * 64 + l;
            const int r = s >> 4;
            const int g = (s & 15) ^ (r & 15);
            GL2LDS(src + r * 64 + g * 4, &Wl[buf][(wv * 256 + k * 64) * 4]);
        }
    };

    const float* ap0 = x + ((size_t)(16 * wv + c) * NI + ig * 8) * 64 + q * 8;
    float4 ra[4], na[4];
    ld_a(ra, ap0);
    stage(0, 0);
    stage(1, 1);
    asm volatile("s_waitcnt vmcnt(0)" ::: "memory");   // prologue drain

    uint2 cst[4];
    #pragma unroll 1
    for (int ii = 0; ii < 8; ++ii) {
        // counted drain: stage(ii) is >=9th-newest at this point for all ii
        // (iter ii-1 issued >=8 vmem ops after it); keeps prefetch in flight.
        asm volatile("s_waitcnt vmcnt(8)" ::: "memory");
        __builtin_amdgcn_s_barrier();        // bar1: buf ii%2 staged
        if (ii > 0) {
            #pragma unroll
            for (int rr = 0; rr < 4; ++rr) {
                const int bq = 16 * wv + 4 * q + rr;
                *(uint2*)(xh + (((size_t)o * NB + bq) * NI + (ig * 8 + ii - 1)) * ND + 4 * c) = cst[rr];
            }
        }
        if (ii < 7) ld_a(na, ap0 + (ii + 1) * 64);

        const float* Wb = Wl[ii & 1];
        const short8 a0 = pack8(ra[0], ra[1]);
        const short8 a1 = pack8(ra[2], ra[3]);
        f32x4 acc[4];
        #pragma unroll
        for (int td = 0; td < 4; ++td) {
            const int r = 16 * td + c;
            const float4 f0 = *(const float4*)&Wb[(r * 16 + ((2 * q)     ^ c)) * 4];
            const float4 f1 = *(const float4*)&Wb[(r * 16 + ((2 * q + 1) ^ c)) * 4];
            const float4 f2 = *(const float4*)&Wb[(r * 16 + ((2 * q + 8) ^ c)) * 4];
            const float4 f3 = *(const float4*)&Wb[(r * 16 + ((2 * q + 9) ^ c)) * 4];
            const short8 b0 = pack8(f0, f1);
            const short8 b1 = pack8(f2, f3);
            f32x4 z = {0.f, 0.f, 0.f, 0.f};
            z = __builtin_amdgcn_mfma_f32_16x16x32_bf16(a0, b0, z, 0, 0, 0);
            z = __builtin_amdgcn_mfma_f32_16x16x32_bf16(a1, b1, z, 0, 0, 0);
            acc[td] = z;
        }
        #pragma unroll
        for (int rr = 0; rr < 4; ++rr) {
            cst[rr].x = (unsigned int)f2bf(acc[0][rr]) | ((unsigned int)f2bf(acc[1][rr]) << 16);
            cst[rr].y = (unsigned int)f2bf(acc[2][rr]) | ((unsigned int)f2bf(acc[3][rr]) << 16);
        }
        #pragma unroll
        for (int j = 0; j < 4; ++j) ra[j] = na[j];

        __builtin_amdgcn_s_barrier();        // bar2: buf ii%2 free for restage
        if (ii < 6) stage(ii & 1, ii + 2);
    }
    #pragma unroll
    for (int rr = 0; rr < 4; ++rr) {
        const int bq = 16 * wv + 4 * q + rr;
        *(uint2*)(xh + (((size_t)o * NB + bq) * NI + (ig * 8 + 7)) * ND + 4 * c) = cst[rr];
    }
}

// Softmax stats per (b,i): m = max_o logits, 1/Z. 128 blocks. (verified)
__global__ __launch_bounds__(256) void k_soft(const float* __restrict__ b_in,
                                              float* __restrict__ mz) {
    const int p = blockIdx.x * 256 + threadIdx.x;        // p = b*512 + i
    const int b = p >> 9, i = p & 511;
    const float* bp = b_in + (size_t)b * NO * NI + i;
    float v[NO];
    #pragma unroll
    for (int oo = 0; oo < NO; ++oo) v[oo] = bp[(size_t)oo * NI];
    float m = v[0];
    #pragma unroll
    for (int oo = 1; oo < NO; ++oo) m = fmaxf(m, v[oo]);
    float Z = 0.f;
    #pragma unroll
    for (int oo = 0; oo < NO; ++oo) Z += __expf(v[oo] - m);
    mz[p] = m;
    mz[NB * NI + p] = 1.0f / Z;
}

// Routing step, block = (b,o). ROUND-12 (unmeasured, resubmit): LDS/reg split
// 256/256 -> 192/320 to raise residency. Routes measured ~100 us at 1.3 TB/s
// with ~5 us VALU -> latency/residency-bound; LDS was 35.3 KB -> 4 blocks/CU.
// New: tile 192 rows (24 KB, total 27.9 KB) -> 5 blocks/CU; reg half 10
// uint4/thread, capped via __launch_bounds__(256,5). Row coverage: global
// k' = 0..15, rows 32k'+ip; k'<6 from LDS, k'>=6 from raw[k'-6]; b-update
// thread stores k'=dg and k'=dg+8 (exactly 2 rows/thread).
template<int STEP>
__global__ __launch_bounds__(256, 5) void k_route(const unsigned short* __restrict__ xh,
                                                  const float* __restrict__ b_in,
                                                  const float* __restrict__ mz,
                                                  float* __restrict__ b_out,
                                                  float* __restrict__ outp) {
    __shared__ unsigned short tile[192 * ND];  // 24 KB, rows 0..191
    __shared__ float c_s[NI];
    __shared__ float P[4 * 64];
    __shared__ float o_s[64];

    const int t  = threadIdx.x;
    const int b  = blockIdx.x >> 5;
    const int o  = blockIdx.x & 31;
    const int wv = t >> 6;
    const int l  = t & 63;
    const int dg = t & 7;
    const int ip = t >> 3;

    const unsigned short* gsrc = xh + ((size_t)o * NB + b) * NI * ND;

    // Register half first (latency overlapped by DMA issue + softmax):
    // rows 192 + 32k + ip, k = 0..9.
    uint4 raw[10];
    #pragma unroll
    for (int k = 0; k < 10; ++k)
        raw[k] = *(const uint4*)(gsrc + (size_t)(192 + 32 * k + ip) * ND + dg * 8);

    // DMA half: 192 rows = 24 KB; wave wv covers 6 KB as 6 x 1-KB instrs.
    #pragma unroll
    for (int k = 0; k < 6; ++k)
        GL2LDS(gsrc + wv * 3072 + k * 512 + l * 8, tile + wv * 3072 + k * 512);

    const float* bp = (STEP > 0) ? (b_in + ((size_t)b * NO + o) * NI) : nullptr;
    if (STEP > 0) {
        const float* mrow = mz + (size_t)b * NI;
        const float* zrow = mz + (size_t)(NB * NI) + (size_t)b * NI;
        #pragma unroll
        for (int s = 0; s < 2; ++s) {
            const int i = t + s * 256;
            c_s[i] = __expf(bp[i] - mrow[i]) * zrow[i];
        }
    }
    __syncthreads();                                     // DMA + c_s visible

    // c-weighted accumulation of s[d'] over both halves.
    float acc[8] = {0, 0, 0, 0, 0, 0, 0, 0};
    #pragma unroll
    for (int k = 0; k < 6; ++k) {                        // LDS half, rows 32k+ip
        const int i = 32 * k + ip;
        const uint4 rl = *(const uint4*)(tile + i * ND + dg * 8);
        const float cw = (STEP == 0) ? 0.03125f : c_s[i];
        acc[0] += cw * blo(rl.x); acc[1] += cw * bhi(rl.x);
        acc[2] += cw * blo(rl.y); acc[3] += cw * bhi(rl.y);
        acc[4] += cw * blo(rl.z); acc[5] += cw * bhi(rl.z);
        acc[6] += cw * blo(rl.w); acc[7] += cw * bhi(rl.w);
    }
    #pragma unroll
    for (int k = 0; k < 10; ++k) {                       // reg half, rows 192+32k+ip
        const float cw = (STEP == 0) ? 0.03125f : c_s[192 + 32 * k + ip];
        acc[0] += cw * blo(raw[k].x); acc[1] += cw * bhi(raw[k].x);
        acc[2] += cw * blo(raw[k].y); acc[3] += cw * bhi(raw[k].y);
        acc[4] += cw * blo(raw[k].z); acc[5] += cw * bhi(raw[k].z);
        acc[6] += cw * blo(raw[k].w); acc[7] += cw * bhi(raw[k].w);
    }
    #pragma unroll
    for (int j = 0; j < 8; ++j) {          // reduce over ip within wave (bits 3..5)
        acc[j] += __shfl_xor(acc[j], 8);
        acc[j] += __shfl_xor(acc[j], 16);
        acc[j] += __shfl_xor(acc[j], 32);
    }
    if (l < 8) {
        #pragma unroll
        for (int j = 0; j < 8; ++j) P[wv * 64 + l * 8 + j] = acc[j];
    }
    __syncthreads();

    // Wave 0: finish s[d'], squash, emit out vector (o_s in d'-space).
    if (t < 64) {
        const float sv = P[t] + P[64 + t] + P[128 + t] + P[192 + t];
        float s2 = sv * sv;
        #pragma unroll
        for (int m = 1; m < 64; m <<= 1) s2 += __shfl_xor(s2, m);
        const float n = sqrtf(s2);
        const float sc = (s2 / (1.0f + s2)) / (n + 1e-8f);
        const float ov = sv * sc;
        o_s[t] = ov;
        if (STEP == 2) {
            const int d = 16 * (t & 3) + (t >> 2);       // d' -> d remap
            outp[((size_t)b * NO + o) * ND + d] = ov;
        }
    }
    __syncthreads();

    // b-update: dot per row (d'-space), reduce across dg (bits 0..2).
    // Thread (dg,ip) stores rows k'=dg (i1) and k'=dg+8 (i2).
    if (STEP < 2) {
        float oc[8];
        #pragma unroll
        for (int j = 0; j < 8; ++j) oc[j] = o_s[dg * 8 + j];
        float w1 = 0.f, w2 = 0.f;
        #pragma unroll
        for (int k = 0; k < 6; ++k) {                    // LDS rows, k' = 0..5
            const uint4 rl = *(const uint4*)(tile + (32 * k + ip) * ND + dg * 8);
            float pd = blo(rl.x) * oc[0] + bhi(rl.x) * oc[1]
                     + blo(rl.y) * oc[2] + bhi(rl.y) * oc[3]
                     + blo(rl.z) * oc[4] + bhi(rl.z) * oc[5]
                     + blo(rl.w) * oc[6] + bhi(rl.w) * oc[7];
            pd += __shfl_xor(pd, 1);
            pd += __shfl_xor(pd, 2);
            pd += __shfl_xor(pd, 4);
            if (k == dg) w1 = pd;                        // k' = dg (dg < 6)
        }
        #pragma unroll
        for (int k = 0; k < 10; ++k) {                   // reg rows, k' = 6..15
            float pd = blo(raw[k].x) * oc[0] + bhi(raw[k].x) * oc[1]
                     + blo(raw[k].y) * oc[2] + bhi(raw[k].y) * oc[3]
                     + blo(raw[k].z) * oc[4] + bhi(raw[k].z) * oc[5]
                     + blo(raw[k].w) * oc[6] + bhi(raw[k].w) * oc[7];
            pd += __shfl_xor(pd, 1);
            pd += __shfl_xor(pd, 2);
            pd += __shfl_xor(pd, 4);
            if (6 + k == dg) w1 = pd;                    // k' = dg (dg >= 6)
            if (k == dg + 2) w2 = pd;                    // k' = dg + 8
        }
        const int i1 = 32 * dg + ip;                     // row k' = dg
        const int i2 = 256 + 32 * dg + ip;               // row k' = dg + 8
        float* bo = b_out + ((size_t)b * NO + o) * NI;
        bo[i1] = ((STEP == 0) ? 0.f : bp[i1]) + w1;
        bo[i2] = ((STEP == 0) ? 0.f : bp[i2]) + w2;
    }
}

extern "C" void kernel_launch(void* const* d_in, const int* in_sizes, int n_in,
                              void* d_out, int out_size, void* d_ws, size_t ws_size,
                              hipStream_t stream) {
    const float* x = (const float*)d_in[0];        // [64,512,64] fp32
    const float* w = (const float*)d_in[1];        // [32,512,64,64] fp32
    float* outp = (float*)d_out;                   // [64,32,64] fp32

    char* ws = (char*)d_ws;
    unsigned short* xh = (unsigned short*)ws;                       // 128 MiB bf16 xh[o][b][i][d']
    float* ba = (float*)(ws + (size_t)134217728);                   // 4 MiB logits A
    float* bb = (float*)(ws + (size_t)134217728 + 4194304);         // 4 MiB logits B
    float* mz = (float*)(ws + (size_t)134217728 + 2 * 4194304);     // 256 KiB m / 1/Z

    k_gemm<<<dim3(2048), dim3(256), 0, stream>>>(x, w, xh);
    k_route<0><<<dim3(2048), dim3(256), 0, stream>>>(xh, nullptr, nullptr, ba, nullptr);
    k_soft<<<dim3(128), dim3(256), 0, stream>>>(ba, mz);
    k_route<1><<<dim3(2048), dim3(256), 0, stream>>>(xh, ba, mz, bb, nullptr);
    k_soft<<<dim3(128), dim3(256), 0, stream>>>(bb, mz);
    k_route<2><<<dim3(2048), dim3(256), 0, stream>>>(xh, bb, mz, nullptr, outp);
}

// Round 17
// 463.760 us; speedup vs baseline: 1.1433x; 1.1433x over previous
//
#include <hip/hip_runtime.h>
#include <stdint.h>

#define NB 64
#define NO 32
#define NI 512
#define ND 64

typedef __attribute__((ext_vector_type(8))) short short8;
typedef __attribute__((ext_vector_type(4))) float f32x4;

// async global->LDS DMA, 16 B/lane. Global addr per-lane; LDS base wave-uniform,
// lane i lands at base + 16*i (m104/m108 semantics).
#define GL2LDS(g, s) __builtin_amdgcn_global_load_lds( \
    (const __attribute__((address_space(1))) void*)(g), \
    (__attribute__((address_space(3))) void*)(s), 16, 0, 0)

__device__ __forceinline__ float blo(unsigned int u) {
    union { unsigned int i; float f; } v; v.i = u << 16; return v.f;
}
__device__ __forceinline__ float bhi(unsigned int u) {
    union { unsigned int i; float f; } v; v.i = u & 0xFFFF0000u; return v.f;
}
__device__ __forceinline__ unsigned short f2bf(float f) {
    union { float f; unsigned int i; } v; v.f = f;
    return (unsigned short)((v.i + 0x7FFFu + ((v.i >> 16) & 1u)) >> 16);
}
__device__ __forceinline__ short8 pack8(const float4 a, const float4 b) {
    short8 r;
    r[0] = (short)f2bf(a.x); r[1] = (short)f2bf(a.y);
    r[2] = (short)f2bf(a.z); r[3] = (short)f2bf(a.w);
    r[4] = (short)f2bf(b.x); r[5] = (short)f2bf(b.y);
    r[6] = (short)f2bf(b.z); r[7] = (short)f2bf(b.w);
    return r;
}
__device__ __forceinline__ void ld_a(float4 r[4], const float* __restrict__ p) {
    r[0] = *(const float4*)(p);
    r[1] = *(const float4*)(p + 4);
    r[2] = *(const float4*)(p + 32);
    r[3] = *(const float4*)(p + 36);
}

// K1: x_hat = W x, stored bf16 in PERMUTED d-order: d' = 4c + td (d = 16 td + c).
// Layout xh[o][b][i][d']. Counted-vmcnt double-buffer pipeline.
// SESSION LEDGER (final): r10 counted vmcnt(8) + raw s_barrier vs __syncthreads'
// vmcnt(0)-drain: gemm 200 -> <157 us (the attributed win). r11 tbuf->dbuf:
// neutral (occupancy not the limiter). Remaining gap to ~70 us BW floor is
// VALU-bound in-loop W conversion (pack8 x8/iter); bf16-W pre-pass is a wash
// by arithmetic (+61..75 pre-pass vs -60..70 gemm). vmcnt(12) relaxation:
// zero-margin + ii=7 race; rejected.
__global__ __launch_bounds__(256) void k_gemm(const float* __restrict__ x,
                                              const float* __restrict__ w,
                                              unsigned short* __restrict__ xh) {
    __shared__ float Wl[2][4096];            // 32 KB, double-buffered W tiles
    const int o  = blockIdx.x & 31;
    const int ig = blockIdx.x >> 5;
    const int t  = threadIdx.x;
    const int wv = t >> 6;
    const int l  = t & 63;
    const int q  = l >> 4;
    const int c  = l & 15;

    const float* wbase = w + ((size_t)o * NI + ig * 8) * 4096;

    auto stage = [&](int buf, int ii) {
        const float* src = wbase + (size_t)ii * 4096;
        #pragma unroll
        for (int k = 0; k < 4; ++k) {
            const int s = wv * 256 + k * 64 + l;
            const int r = s >> 4;
            const int g = (s & 15) ^ (r & 15);
            GL2LDS(src + r * 64 + g * 4, &Wl[buf][(wv * 256 + k * 64) * 4]);
        }
    };

    const float* ap0 = x + ((size_t)(16 * wv + c) * NI + ig * 8) * 64 + q * 8;
    float4 ra[4], na[4];
    ld_a(ra, ap0);
    stage(0, 0);
    stage(1, 1);
    asm volatile("s_waitcnt vmcnt(0)" ::: "memory");   // prologue drain

    uint2 cst[4];
    #pragma unroll 1
    for (int ii = 0; ii < 8; ++ii) {
        // counted drain: stage(ii) is >=9th-newest at this point for all ii
        // (iter ii-1 issued >=8 vmem ops after it); keeps prefetch in flight.
        asm volatile("s_waitcnt vmcnt(8)" ::: "memory");
        __builtin_amdgcn_s_barrier();        // bar1: buf ii%2 staged
        if (ii > 0) {
            #pragma unroll
            for (int rr = 0; rr < 4; ++rr) {
                const int bq = 16 * wv + 4 * q + rr;
                *(uint2*)(xh + (((size_t)o * NB + bq) * NI + (ig * 8 + ii - 1)) * ND + 4 * c) = cst[rr];
            }
        }
        if (ii < 7) ld_a(na, ap0 + (ii + 1) * 64);

        const float* Wb = Wl[ii & 1];
        const short8 a0 = pack8(ra[0], ra[1]);
        const short8 a1 = pack8(ra[2], ra[3]);
        f32x4 acc[4];
        #pragma unroll
        for (int td = 0; td < 4; ++td) {
            const int r = 16 * td + c;
            const float4 f0 = *(const float4*)&Wb[(r * 16 + ((2 * q)     ^ c)) * 4];
            const float4 f1 = *(const float4*)&Wb[(r * 16 + ((2 * q + 1) ^ c)) * 4];
            const float4 f2 = *(const float4*)&Wb[(r * 16 + ((2 * q + 8) ^ c)) * 4];
            const float4 f3 = *(const float4*)&Wb[(r * 16 + ((2 * q + 9) ^ c)) * 4];
            const short8 b0 = pack8(f0, f1);
            const short8 b1 = pack8(f2, f3);
            f32x4 z = {0.f, 0.f, 0.f, 0.f};
            z = __builtin_amdgcn_mfma_f32_16x16x32_bf16(a0, b0, z, 0, 0, 0);
            z = __builtin_amdgcn_mfma_f32_16x16x32_bf16(a1, b1, z, 0, 0, 0);
            acc[td] = z;
        }
        #pragma unroll
        for (int rr = 0; rr < 4; ++rr) {
            cst[rr].x = (unsigned int)f2bf(acc[0][rr]) | ((unsigned int)f2bf(acc[1][rr]) << 16);
            cst[rr].y = (unsigned int)f2bf(acc[2][rr]) | ((unsigned int)f2bf(acc[3][rr]) << 16);
        }
        #pragma unroll
        for (int j = 0; j < 4; ++j) ra[j] = na[j];

        __builtin_amdgcn_s_barrier();        // bar2: buf ii%2 free for restage
        if (ii < 6) stage(ii & 1, ii + 2);
    }
    #pragma unroll
    for (int rr = 0; rr < 4; ++rr) {
        const int bq = 16 * wv + 4 * q + rr;
        *(uint2*)(xh + (((size_t)o * NB + bq) * NI + (ig * 8 + 7)) * ND + 4 * c) = cst[rr];
    }
}

// Softmax stats per (b,i): m = max_o logits, 1/Z. 128 blocks. (verified)
__global__ __launch_bounds__(256) void k_soft(const float* __restrict__ b_in,
                                              float* __restrict__ mz) {
    const int p = blockIdx.x * 256 + threadIdx.x;        // p = b*512 + i
    const int b = p >> 9, i = p & 511;
    const float* bp = b_in + (size_t)b * NO * NI + i;
    float v[NO];
    #pragma unroll
    for (int oo = 0; oo < NO; ++oo) v[oo] = bp[(size_t)oo * NI];
    float m = v[0];
    #pragma unroll
    for (int oo = 1; oo < NO; ++oo) m = fmaxf(m, v[oo]);
    float Z = 0.f;
    #pragma unroll
    for (int oo = 0; oo < NO; ++oo) Z += __expf(v[oo] - m);
    mz[p] = m;
    mz[NB * NI + p] = 1.0f / Z;
}

// Routing step, block = (b,o). Measured-best 256/256 hybrid split (r14's
// 192/320 + 5-wave cap regressed 464->530: register pressure, not LDS, binds
// this kernel). Rows 0..255 DMA'd to LDS (32 KB), rows 256..511 in registers
// (8 uint4/thread). All d-indexed data in d'-space; STEP==2 output remaps
// d = 16*(t&3)+(t>>2). Route limiter (1.3 TB/s vs 6.7 achievable) remains
// uncharacterized after 5 falsified theories; counters unobtainable (routes
// rank below harness fillBuffer in top-5).
template<int STEP>
__global__ __launch_bounds__(256) void k_route(const unsigned short* __restrict__ xh,
                                               const float* __restrict__ b_in,
                                               const float* __restrict__ mz,
                                               float* __restrict__ b_out,
                                               float* __restrict__ outp) {
    __shared__ unsigned short tile[256 * ND];  // 32 KB, rows 0..255
    __shared__ float c_s[NI];
    __shared__ float P[4 * 64];
    __shared__ float o_s[64];

    const int t  = threadIdx.x;
    const int b  = blockIdx.x >> 5;
    const int o  = blockIdx.x & 31;
    const int wv = t >> 6;
    const int l  = t & 63;
    const int dg = t & 7;
    const int ip = t >> 3;

    const unsigned short* gsrc = xh + ((size_t)o * NB + b) * NI * ND;

    // Register half first (latency overlapped by DMA issue + softmax).
    uint4 raw[8];
    #pragma unroll
    for (int k = 0; k < 8; ++k)
        raw[k] = *(const uint4*)(gsrc + (size_t)(256 + 32 * k + ip) * ND + dg * 8);

    // DMA half: wave wv covers 8 KB as 8 x 1-KB instrs (linear layout).
    #pragma unroll
    for (int k = 0; k < 8; ++k)
        GL2LDS(gsrc + wv * 4096 + k * 512 + l * 8, tile + wv * 4096 + k * 512);

    const float* bp = (STEP > 0) ? (b_in + ((size_t)b * NO + o) * NI) : nullptr;
    if (STEP > 0) {
        const float* mrow = mz + (size_t)b * NI;
        const float* zrow = mz + (size_t)(NB * NI) + (size_t)b * NI;
        #pragma unroll
        for (int s = 0; s < 2; ++s) {
            const int i = t + s * 256;
            c_s[i] = __expf(bp[i] - mrow[i]) * zrow[i];
        }
    }
    __syncthreads();                                     // DMA + c_s visible

    // c-weighted accumulation of s[d'] over both halves.
    float acc[8] = {0, 0, 0, 0, 0, 0, 0, 0};
    #pragma unroll
    for (int k = 0; k < 8; ++k) {                        // LDS half, rows 32k+ip
        const int i = 32 * k + ip;
        const uint4 rl = *(const uint4*)(tile + i * ND + dg * 8);
        const float cw = (STEP == 0) ? 0.03125f : c_s[i];
        acc[0] += cw * blo(rl.x); acc[1] += cw * bhi(rl.x);
        acc[2] += cw * blo(rl.y); acc[3] += cw * bhi(rl.y);
        acc[4] += cw * blo(rl.z); acc[5] += cw * bhi(rl.z);
        acc[6] += cw * blo(rl.w); acc[7] += cw * bhi(rl.w);
    }
    #pragma unroll
    for (int k = 0; k < 8; ++k) {                        // register half, rows 256+32k+ip
        const float cw = (STEP == 0) ? 0.03125f : c_s[256 + 32 * k + ip];
        acc[0] += cw * blo(raw[k].x); acc[1] += cw * bhi(raw[k].x);
        acc[2] += cw * blo(raw[k].y); acc[3] += cw * bhi(raw[k].y);
        acc[4] += cw * blo(raw[k].z); acc[5] += cw * bhi(raw[k].z);
        acc[6] += cw * blo(raw[k].w); acc[7] += cw * bhi(raw[k].w);
    }
    #pragma unroll
    for (int j = 0; j < 8; ++j) {          // reduce over ip within wave (bits 3..5)
        acc[j] += __shfl_xor(acc[j], 8);
        acc[j] += __shfl_xor(acc[j], 16);
        acc[j] += __shfl_xor(acc[j], 32);
    }
    if (l < 8) {
        #pragma unroll
        for (int j = 0; j < 8; ++j) P[wv * 64 + l * 8 + j] = acc[j];
    }
    __syncthreads();

    // Wave 0: finish s[d'], squash, emit out vector (o_s in d'-space).
    if (t < 64) {
        const float sv = P[t] + P[64 + t] + P[128 + t] + P[192 + t];
        float s2 = sv * sv;
        #pragma unroll
        for (int m = 1; m < 64; m <<= 1) s2 += __shfl_xor(s2, m);
        const float n = sqrtf(s2);
        const float sc = (s2 / (1.0f + s2)) / (n + 1e-8f);
        const float ov = sv * sc;
        o_s[t] = ov;
        if (STEP == 2) {
            const int d = 16 * (t & 3) + (t >> 2);       // d' -> d remap
            outp[((size_t)b * NO + o) * ND + d] = ov;
        }
    }
    __syncthreads();

    // b-update: dot per row (d'-space), reduce across dg (bits 0..2).
    if (STEP < 2) {
        float oc[8];
        #pragma unroll
        for (int j = 0; j < 8; ++j) oc[j] = o_s[dg * 8 + j];
        float w1 = 0.f, w2 = 0.f;
        #pragma unroll
        for (int k = 0; k < 8; ++k) {                    // LDS half
            const uint4 rl = *(const uint4*)(tile + (32 * k + ip) * ND + dg * 8);
            float pd = blo(rl.x) * oc[0] + bhi(rl.x) * oc[1]
                     + blo(rl.y) * oc[2] + bhi(rl.y) * oc[3]
                     + blo(rl.z) * oc[4] + bhi(rl.z) * oc[5]
                     + blo(rl.w) * oc[6] + bhi(rl.w) * oc[7];
            pd += __shfl_xor(pd, 1);
            pd += __shfl_xor(pd, 2);
            pd += __shfl_xor(pd, 4);
            if (k == dg) w1 = pd;
        }
        #pragma unroll
        for (int k = 0; k < 8; ++k) {                    // register half
            float pd = blo(raw[k].x) * oc[0] + bhi(raw[k].x) * oc[1]
                     + blo(raw[k].y) * oc[2] + bhi(raw[k].y) * oc[3]
                     + blo(raw[k].z) * oc[4] + bhi(raw[k].z) * oc[5]
                     + blo(raw[k].w) * oc[6] + bhi(raw[k].w) * oc[7];
            pd += __shfl_xor(pd, 1);
            pd += __shfl_xor(pd, 2);
            pd += __shfl_xor(pd, 4);
            if (k == dg) w2 = pd;
        }
        const int i1 = 32 * dg + ip;                     // row from LDS half
        const int i2 = 256 + 32 * dg + ip;               // row from register half
        float* bo = b_out + ((size_t)b * NO + o) * NI;
        bo[i1] = ((STEP == 0) ? 0.f : bp[i1]) + w1;
        bo[i2] = ((STEP == 0) ? 0.f : bp[i2]) + w2;
    }
}

extern "C" void kernel_launch(void* const* d_in, const int* in_sizes, int n_in,
                              void* d_out, int out_size, void* d_ws, size_t ws_size,
                              hipStream_t stream) {
    const float* x = (const float*)d_in[0];        // [64,512,64] fp32
    const float* w = (const float*)d_in[1];        // [32,512,64,64] fp32
    float* outp = (float*)d_out;                   // [64,32,64] fp32

    char* ws = (char*)d_ws;
    unsigned short* xh = (unsigned short*)ws;                       // 128 MiB bf16 xh[o][b][i][d']
    float* ba = (float*)(ws + (size_t)134217728);                   // 4 MiB logits A
    float* bb = (float*)(ws + (size_t)134217728 + 4194304);         // 4 MiB logits B
    float* mz = (float*)(ws + (size_t)134217728 + 2 * 4194304);     // 256 KiB m / 1/Z

    k_gemm<<<dim3(2048), dim3(256), 0, stream>>>(x, w, xh);
    k_route<0><<<dim3(2048), dim3(256), 0, stream>>>(xh, nullptr, nullptr, ba, nullptr);
    k_soft<<<dim3(128), dim3(256), 0, stream>>>(ba, mz);
    k_route<1><<<dim3(2048), dim3(256), 0, stream>>>(xh, ba, mz, bb, nullptr);
    k_soft<<<dim3(128), dim3(256), 0, stream>>>(bb, mz);
    k_route<2><<<dim3(2048), dim3(256), 0, stream>>>(xh, bb, mz, nullptr, outp);
}